// Round 2
// baseline (3407.466 us; speedup 1.0000x reference)
//
#include <hip/hip_runtime.h>

#define Tn 200
#define Dn 64
#define Hn 64
#define CC 16   // timesteps per LDS chunk

__device__ __forceinline__ float fast_sigmoid(float v) {
    // 1/(1+e^-v); stable at both ends via rcp(inf)=0
    return __builtin_amdgcn_rcpf(1.0f + __expf(-v));
}
__device__ __forceinline__ float fast_tanh(float v) {
    return 1.0f - 2.0f * __builtin_amdgcn_rcpf(1.0f + __expf(2.0f * v));
}
// Intra-wave LDS ordering: wave writes LDS then other lanes read it.
// Wave64 executes in lockstep; we only need the lgkm queue drained and the
// compiler prevented from reordering across it.
__device__ __forceinline__ void wave_lds_fence() {
    asm volatile("s_waitcnt lgkmcnt(0)" ::: "memory");
}

__global__ __launch_bounds__(128, 2)
void augru_fused(const float* __restrict__ x,     // [B,T,D]
                 const int*   __restrict__ slen,  // [B]
                 const float* __restrict__ att,   // [B,T]
                 const float* __restrict__ gk,    // [128][128] cols r|u
                 const float* __restrict__ gb,    // [128]
                 const float* __restrict__ ck,    // [128][64]
                 const float* __restrict__ cb,    // [64]
                 float* __restrict__ out)         // [B,T,H]
{
    const int b    = blockIdx.x;
    const int tid  = threadIdx.x;
    const int wave = tid >> 6;
    const int j    = tid & 63;

    __shared__ float s_P[2][CC][3][Hn];  // [buf][t][r|u|c][col] pre-activations (x part + bias)
    __shared__ float s_att[2][CC];
    __shared__ float s_h[Hn];
    __shared__ float s_rh[Hn];

    const int len     = slen[b];
    const int nchunks = (len + CC - 1) / CC;

    const float* xrow = x   + (size_t)b * Tn * Dn;
    const float* arow = att + (size_t)b * Tn;
    float*       orow = out + (size_t)b * Tn * Hn;

    if (wave == 0) {
        // ================= producer: P[t] = x_t @ W_x + bias =================
        float wr[64], wu[64], wc[64];   // x-part weight columns for lane j
#pragma unroll
        for (int k = 0; k < 64; ++k) {
            wr[k] = gk[k * 128 + j];
            wu[k] = gk[k * 128 + 64 + j];
            wc[k] = ck[k * 64 + j];
        }
        const float br = gb[j], bu = gb[64 + j], bc = cb[j];

        for (int c = 0; c < nchunks; ++c) {
            const int t0   = c * CC;
            const int tend = min(len, t0 + CC);
            for (int t = t0; t < tend; ++t) {
                const float4* xv = (const float4*)(xrow + t * Dn);  // lane-uniform
                float r0 = br, r1 = 0.f, u0 = bu, u1 = 0.f, c0 = bc, c1 = 0.f;
#pragma unroll
                for (int kk = 0; kk < 16; ++kk) {
                    const float4 q = xv[kk];
                    const int k = kk * 4;
                    r0 = fmaf(q.x, wr[k],     r0);
                    r1 = fmaf(q.y, wr[k + 1], r1);
                    r0 = fmaf(q.z, wr[k + 2], r0);
                    r1 = fmaf(q.w, wr[k + 3], r1);
                    u0 = fmaf(q.x, wu[k],     u0);
                    u1 = fmaf(q.y, wu[k + 1], u1);
                    u0 = fmaf(q.z, wu[k + 2], u0);
                    u1 = fmaf(q.w, wu[k + 3], u1);
                    c0 = fmaf(q.x, wc[k],     c0);
                    c1 = fmaf(q.y, wc[k + 1], c1);
                    c0 = fmaf(q.z, wc[k + 2], c0);
                    c1 = fmaf(q.w, wc[k + 3], c1);
                }
                const int lt = t - t0;
                s_P[c & 1][lt][0][j] = r0 + r1;
                s_P[c & 1][lt][1][j] = u0 + u1;
                s_P[c & 1][lt][2][j] = c0 + c1;
            }
            if (j < tend - t0) s_att[c & 1][j] = arow[t0 + j];
            __syncthreads();  // hand buffer c&1 to consumer
        }
    } else {
        // ================= consumer: serial recurrence =================
        float wr[64], wu[64], wc[64];   // h-part weight columns (rows 64..127)
#pragma unroll
        for (int k = 0; k < 64; ++k) {
            wr[k] = gk[(64 + k) * 128 + j];
            wu[k] = gk[(64 + k) * 128 + 64 + j];
            wc[k] = ck[(64 + k) * 64 + j];
        }
        float h = 0.0f;

        for (int c = 0; c < nchunks; ++c) {
            __syncthreads();  // wait for producer fill of buffer c&1
            const int t0   = c * CC;
            const int tend = min(len, t0 + CC);
            for (int t = t0; t < tend; ++t) {
                const int lt = t - t0;
                s_h[j] = h;
                wave_lds_fence();

                float r0 = s_P[c & 1][lt][0][j], r1 = 0.f;
                float u0 = s_P[c & 1][lt][1][j], u1 = 0.f;
                const float4* hv = (const float4*)s_h;  // broadcast
#pragma unroll
                for (int kk = 0; kk < 16; ++kk) {
                    const float4 q = hv[kk];
                    const int k = kk * 4;
                    r0 = fmaf(q.x, wr[k],     r0);
                    r1 = fmaf(q.y, wr[k + 1], r1);
                    r0 = fmaf(q.z, wr[k + 2], r0);
                    r1 = fmaf(q.w, wr[k + 3], r1);
                    u0 = fmaf(q.x, wu[k],     u0);
                    u1 = fmaf(q.y, wu[k + 1], u1);
                    u0 = fmaf(q.z, wu[k + 2], u0);
                    u1 = fmaf(q.w, wu[k + 3], u1);
                }
                const float rg = fast_sigmoid(r0 + r1);
                const float ug = fast_sigmoid(u0 + u1);

                s_rh[j] = rg * h;
                wave_lds_fence();

                float c0 = s_P[c & 1][lt][2][j], c1 = 0.f;
                const float4* rhv = (const float4*)s_rh;
#pragma unroll
                for (int kk = 0; kk < 16; ++kk) {
                    const float4 q = rhv[kk];
                    const int k = kk * 4;
                    c0 = fmaf(q.x, wc[k],     c0);
                    c1 = fmaf(q.y, wc[k + 1], c1);
                    c0 = fmaf(q.z, wc[k + 2], c0);
                    c1 = fmaf(q.w, wc[k + 3], c1);
                }
                const float cg = fast_tanh(c0 + c1);

                const float a  = s_att[c & 1][lt];
                const float uh = (1.0f - a) * ug;
                h = uh * h + (1.0f - uh) * cg;
                orow[t * Hn + j] = h;
                wave_lds_fence();  // WAR: s_h/s_rh reads done before next t's writes
            }
        }
    }

    // ---- zero tail: out[b, len:T, :] = 0 (both waves) ----
    float4 z;
    z.x = z.y = z.z = z.w = 0.0f;
    float* tail = orow + len * Hn;
    const int total = (Tn - len) * Hn;
    for (int i = tid * 4; i < total; i += 128 * 4) {
        *(float4*)(tail + i) = z;
    }
}

extern "C" void kernel_launch(void* const* d_in, const int* in_sizes, int n_in,
                              void* d_out, int out_size, void* d_ws, size_t ws_size,
                              hipStream_t stream) {
    const float* x    = (const float*)d_in[0];
    const int*   slen = (const int*)  d_in[1];
    const float* att  = (const float*)d_in[2];
    const float* gk   = (const float*)d_in[3];
    const float* gb   = (const float*)d_in[4];
    const float* ck   = (const float*)d_in[5];
    const float* cb   = (const float*)d_in[6];
    float* out = (float*)d_out;

    const int B = in_sizes[1];  // 2048
    augru_fused<<<B, 128, 0, stream>>>(x, slen, att, gk, gb, ck, cb, out);
}

// Round 3
// 1438.972 us; speedup vs baseline: 2.3680x; 2.3680x over previous
//
#include <hip/hip_runtime.h>

#define Tn 200
#define Dn 64
#define Hn 64
#define CC 16   // timesteps per LDS chunk

__device__ __forceinline__ float fast_sigmoid(float v) {
    return __builtin_amdgcn_rcpf(1.0f + __expf(-v));
}
__device__ __forceinline__ float fast_tanh(float v) {
    return 1.0f - 2.0f * __builtin_amdgcn_rcpf(1.0f + __expf(2.0f * v));
}
// Intra-wave LDS ordering (wave64 lockstep): drain lgkm queue + compiler fence.
__device__ __forceinline__ void wave_lds_fence() {
    asm volatile("s_waitcnt lgkmcnt(0)" ::: "memory");
}

// min-waves-per-EU = 1 -> 512-VGPR budget: the 48 float4 weight regs (192
// floats) MUST stay in VGPRs. (128,2) capped at 256 and demoted them to
// scratch: 2 GB HBM scratch traffic, 3.3 ms. Do not raise occupancy here.
__global__ __launch_bounds__(128, 1)
void augru_fused(const float* __restrict__ x,     // [B,T,D]
                 const int*   __restrict__ slen,  // [B]
                 const float* __restrict__ att,   // [B,T]
                 const float* __restrict__ gk,    // [128][128] cols r|u
                 const float* __restrict__ gb,    // [128]
                 const float* __restrict__ ck,    // [128][64]
                 const float* __restrict__ cb,    // [64]
                 float* __restrict__ out)         // [B,T,H]
{
    const int b    = blockIdx.x;
    const int tid  = threadIdx.x;
    const int wave = tid >> 6;
    const int j    = tid & 63;

    __shared__ float s_P[2][CC][3][Hn];  // [buf][t][r|u|c][col] x-part pre-activations
    __shared__ float s_att[2][CC];
    __shared__ float s_h[Hn];
    __shared__ float s_rh[Hn];

    const int len     = slen[b];
    const int nchunks = (len + CC - 1) / CC;

    const float* xrow = x   + (size_t)b * Tn * Dn;
    const float* arow = att + (size_t)b * Tn;
    float*       orow = out + (size_t)b * Tn * Hn;

    if (wave == 0) {
        // ============ producer: P[t] = x_t @ W_x + bias (time-parallel) ============
        float4 wr[16], wu[16], wc[16];   // x-part weight columns for lane j
#pragma unroll
        for (int kk = 0; kk < 16; ++kk) {
            const int k = kk * 4;
            wr[kk].x = gk[(k + 0) * 128 + j];
            wr[kk].y = gk[(k + 1) * 128 + j];
            wr[kk].z = gk[(k + 2) * 128 + j];
            wr[kk].w = gk[(k + 3) * 128 + j];
            wu[kk].x = gk[(k + 0) * 128 + 64 + j];
            wu[kk].y = gk[(k + 1) * 128 + 64 + j];
            wu[kk].z = gk[(k + 2) * 128 + 64 + j];
            wu[kk].w = gk[(k + 3) * 128 + 64 + j];
            wc[kk].x = ck[(k + 0) * 64 + j];
            wc[kk].y = ck[(k + 1) * 64 + j];
            wc[kk].z = ck[(k + 2) * 64 + j];
            wc[kk].w = ck[(k + 3) * 64 + j];
        }
        const float br = gb[j], bu = gb[64 + j], bc = cb[j];

        for (int c = 0; c < nchunks; ++c) {
            const int t0   = c * CC;
            const int tend = min(len, t0 + CC);
            for (int t = t0; t < tend; ++t) {
                const float4* xv = (const float4*)(xrow + t * Dn);  // lane-uniform
                float r0 = br, r1 = 0.f, u0 = bu, u1 = 0.f, c0 = bc, c1 = 0.f;
#pragma unroll
                for (int kk = 0; kk < 16; ++kk) {
                    const float4 q = xv[kk];
                    const float4 a = wr[kk], bq = wu[kk], cq = wc[kk];
                    r0 = fmaf(q.x, a.x, r0);  r1 = fmaf(q.y, a.y, r1);
                    r0 = fmaf(q.z, a.z, r0);  r1 = fmaf(q.w, a.w, r1);
                    u0 = fmaf(q.x, bq.x, u0); u1 = fmaf(q.y, bq.y, u1);
                    u0 = fmaf(q.z, bq.z, u0); u1 = fmaf(q.w, bq.w, u1);
                    c0 = fmaf(q.x, cq.x, c0); c1 = fmaf(q.y, cq.y, c1);
                    c0 = fmaf(q.z, cq.z, c0); c1 = fmaf(q.w, cq.w, c1);
                }
                const int lt = t - t0;
                s_P[c & 1][lt][0][j] = r0 + r1;
                s_P[c & 1][lt][1][j] = u0 + u1;
                s_P[c & 1][lt][2][j] = c0 + c1;
            }
            if (j < tend - t0) s_att[c & 1][j] = arow[t0 + j];
            __syncthreads();  // hand buffer c&1 to consumer
        }
    } else {
        // ============ consumer: serial recurrence over t ============
        float4 wr[16], wu[16], wc[16];   // h-part weight columns (rows 64..127)
#pragma unroll
        for (int kk = 0; kk < 16; ++kk) {
            const int k = 64 + kk * 4;
            wr[kk].x = gk[(k + 0) * 128 + j];
            wr[kk].y = gk[(k + 1) * 128 + j];
            wr[kk].z = gk[(k + 2) * 128 + j];
            wr[kk].w = gk[(k + 3) * 128 + j];
            wu[kk].x = gk[(k + 0) * 128 + 64 + j];
            wu[kk].y = gk[(k + 1) * 128 + 64 + j];
            wu[kk].z = gk[(k + 2) * 128 + 64 + j];
            wu[kk].w = gk[(k + 3) * 128 + 64 + j];
            wc[kk].x = ck[(k + 0) * 64 + j];
            wc[kk].y = ck[(k + 1) * 64 + j];
            wc[kk].z = ck[(k + 2) * 64 + j];
            wc[kk].w = ck[(k + 3) * 64 + j];
        }
        float h = 0.0f;

        for (int c = 0; c < nchunks; ++c) {
            __syncthreads();  // wait for producer fill of buffer c&1
            const int t0   = c * CC;
            const int tend = min(len, t0 + CC);
            for (int t = t0; t < tend; ++t) {
                const int lt = t - t0;
                s_h[j] = h;
                wave_lds_fence();

                float r0 = s_P[c & 1][lt][0][j], r1 = 0.f;
                float u0 = s_P[c & 1][lt][1][j], u1 = 0.f;
                const float4* hv = (const float4*)s_h;  // broadcast
#pragma unroll
                for (int kk = 0; kk < 16; ++kk) {
                    const float4 q = hv[kk];
                    const float4 a = wr[kk], bq = wu[kk];
                    r0 = fmaf(q.x, a.x, r0);  r1 = fmaf(q.y, a.y, r1);
                    r0 = fmaf(q.z, a.z, r0);  r1 = fmaf(q.w, a.w, r1);
                    u0 = fmaf(q.x, bq.x, u0); u1 = fmaf(q.y, bq.y, u1);
                    u0 = fmaf(q.z, bq.z, u0); u1 = fmaf(q.w, bq.w, u1);
                }
                const float rg = fast_sigmoid(r0 + r1);
                const float ug = fast_sigmoid(u0 + u1);

                s_rh[j] = rg * h;
                wave_lds_fence();

                float c0 = s_P[c & 1][lt][2][j], c1 = 0.f;
                const float4* rhv = (const float4*)s_rh;
#pragma unroll
                for (int kk = 0; kk < 16; ++kk) {
                    const float4 q = rhv[kk];
                    const float4 cq = wc[kk];
                    c0 = fmaf(q.x, cq.x, c0); c1 = fmaf(q.y, cq.y, c1);
                    c0 = fmaf(q.z, cq.z, c0); c1 = fmaf(q.w, cq.w, c1);
                }
                const float cg = fast_tanh(c0 + c1);

                const float a  = s_att[c & 1][lt];
                const float uh = (1.0f - a) * ug;
                h = uh * h + (1.0f - uh) * cg;
                orow[t * Hn + j] = h;
                wave_lds_fence();  // WAR before next t's s_h/s_rh writes
            }
        }
    }

    // ---- zero tail: out[b, len:T, :] = 0 ----
    float4 z;
    z.x = z.y = z.z = z.w = 0.0f;
    float* tail = orow + len * Hn;
    const int total = (Tn - len) * Hn;
    for (int i = tid * 4; i < total; i += 128 * 4) {
        *(float4*)(tail + i) = z;
    }
}

extern "C" void kernel_launch(void* const* d_in, const int* in_sizes, int n_in,
                              void* d_out, int out_size, void* d_ws, size_t ws_size,
                              hipStream_t stream) {
    const float* x    = (const float*)d_in[0];
    const int*   slen = (const int*)  d_in[1];
    const float* att  = (const float*)d_in[2];
    const float* gk   = (const float*)d_in[3];
    const float* gb   = (const float*)d_in[4];
    const float* ck   = (const float*)d_in[5];
    const float* cb   = (const float*)d_in[6];
    float* out = (float*)d_out;

    const int B = in_sizes[1];  // 2048
    augru_fused<<<B, 128, 0, stream>>>(x, slen, att, gk, gb, ck, cb, out);
}

// Round 4
// 561.192 us; speedup vs baseline: 6.0718x; 2.5641x over previous
//
#include <hip/hip_runtime.h>

#define Tn 200
#define Dn 64
#define Hn 64
#define CC 16   // timesteps per LDS chunk

typedef _Float16 half2v __attribute__((ext_vector_type(2)));
typedef _Float16 half8v __attribute__((ext_vector_type(8)));

__device__ __forceinline__ float fast_sigmoid(float v) {
    return __builtin_amdgcn_rcpf(1.0f + __expf(-v));
}
__device__ __forceinline__ float fast_tanh(float v) {
    return 1.0f - 2.0f * __builtin_amdgcn_rcpf(1.0f + __expf(2.0f * v));
}
// Intra-wave LDS ordering (wave64 lockstep): drain lgkm queue + compiler fence.
__device__ __forceinline__ void wave_lds_fence() {
    asm volatile("s_waitcnt lgkmcnt(0)" ::: "memory");
}

// fp16-packed weights: 96 half2 VGPRs per branch (fp32 needed 192 VGPRs and
// pinned the kernel at the 256 arch-VGPR cliff -> scratch spills, 380 MB
// FETCH). fdot2 = 2 MACs/inst, fp32 accumulate.
__global__ __launch_bounds__(128, 2)
void augru_fused(const float* __restrict__ x,     // [B,T,D]
                 const int*   __restrict__ slen,  // [B]
                 const float* __restrict__ att,   // [B,T]
                 const float* __restrict__ gk,    // [128][128] cols r|u
                 const float* __restrict__ gb,    // [128]
                 const float* __restrict__ ck,    // [128][64]
                 const float* __restrict__ cb,    // [64]
                 float* __restrict__ out)         // [B,T,H]
{
    const int b    = blockIdx.x;
    const int tid  = threadIdx.x;
    const int wave = tid >> 6;
    const int j    = tid & 63;

    __shared__ float s_P[2][CC][3][Hn];          // x-part pre-activations (fp32)
    __shared__ __align__(16) _Float16 s_h[Hn];
    __shared__ __align__(16) _Float16 s_rh[Hn];

    const int len     = slen[b];
    const int nchunks = (len + CC - 1) / CC;

    const float* xrow = x   + (size_t)b * Tn * Dn;
    const float* arow = att + (size_t)b * Tn;
    float*       orow = out + (size_t)b * Tn * Hn;

    if (wave == 0) {
        // ========== producer: P[t] = x_t @ W_x + bias (time-parallel) ==========
        half2v wr[32], wu[32], wc[32];   // x-part weight cols (K rows 0..63), packed pairs
#pragma unroll
        for (int m = 0; m < 32; ++m) {
            const int k = 2 * m;
            wr[m] = half2v{(_Float16)gk[(k + 0) * 128 + j],
                           (_Float16)gk[(k + 1) * 128 + j]};
            wu[m] = half2v{(_Float16)gk[(k + 0) * 128 + 64 + j],
                           (_Float16)gk[(k + 1) * 128 + 64 + j]};
            wc[m] = half2v{(_Float16)ck[(k + 0) * 64 + j],
                           (_Float16)ck[(k + 1) * 64 + j]};
        }
        const float br = gb[j], bu = gb[64 + j], bc = cb[j];

        for (int c = 0; c < nchunks; ++c) {
            const int t0   = c * CC;
            const int tend = min(len, t0 + CC);
            for (int t = t0; t < tend; ++t) {
                const float4* xv = (const float4*)(xrow + t * Dn);  // lane-uniform
                float r0 = br, r1 = 0.f, u0 = bu, u1 = 0.f, c0 = bc, c1 = 0.f;
#pragma unroll
                for (int kk = 0; kk < 16; ++kk) {
                    const float4 q = xv[kk];
                    const half2v p0 = half2v{(_Float16)q.x, (_Float16)q.y};
                    const half2v p1 = half2v{(_Float16)q.z, (_Float16)q.w};
                    const int m = 2 * kk;
                    r0 = __builtin_amdgcn_fdot2(p0, wr[m],     r0, false);
                    r1 = __builtin_amdgcn_fdot2(p1, wr[m + 1], r1, false);
                    u0 = __builtin_amdgcn_fdot2(p0, wu[m],     u0, false);
                    u1 = __builtin_amdgcn_fdot2(p1, wu[m + 1], u1, false);
                    c0 = __builtin_amdgcn_fdot2(p0, wc[m],     c0, false);
                    c1 = __builtin_amdgcn_fdot2(p1, wc[m + 1], c1, false);
                }
                const int lt = t - t0;
                s_P[c & 1][lt][0][j] = r0 + r1;
                s_P[c & 1][lt][1][j] = u0 + u1;
                s_P[c & 1][lt][2][j] = c0 + c1;
            }
            __syncthreads();  // hand buffer c&1 to consumer
        }
    } else {
        // ========== consumer: serial recurrence over t ==========
        half2v wr[32], wu[32], wc[32];   // h-part weight cols (K rows 64..127)
#pragma unroll
        for (int m = 0; m < 32; ++m) {
            const int k = 64 + 2 * m;
            wr[m] = half2v{(_Float16)gk[(k + 0) * 128 + j],
                           (_Float16)gk[(k + 1) * 128 + j]};
            wu[m] = half2v{(_Float16)gk[(k + 0) * 128 + 64 + j],
                           (_Float16)gk[(k + 1) * 128 + 64 + j]};
            wc[m] = half2v{(_Float16)ck[(k + 0) * 64 + j],
                           (_Float16)ck[(k + 1) * 64 + j]};
        }
        float h = 0.0f;

        for (int c = 0; c < nchunks; ++c) {
            __syncthreads();  // wait for producer fill of buffer c&1
            const int t0   = c * CC;
            const int tend = min(len, t0 + CC);
            for (int t = t0; t < tend; ++t) {
                const int lt = t - t0;
                // prefetch step inputs (independent of h chain)
                const float pr = s_P[c & 1][lt][0][j];
                const float pu = s_P[c & 1][lt][1][j];
                const float pc = s_P[c & 1][lt][2][j];
                const float a  = arow[t];

                s_h[j] = (_Float16)h;
                wave_lds_fence();

                float r0 = pr, r1 = 0.f, u0 = pu, u1 = 0.f;
                const half8v* hv = (const half8v*)s_h;   // 8 x 16B broadcast reads
#pragma unroll
                for (int m8 = 0; m8 < 8; ++m8) {
                    const half8v v = hv[m8];
                    const half2v p0 = __builtin_shufflevector(v, v, 0, 1);
                    const half2v p1 = __builtin_shufflevector(v, v, 2, 3);
                    const half2v p2 = __builtin_shufflevector(v, v, 4, 5);
                    const half2v p3 = __builtin_shufflevector(v, v, 6, 7);
                    const int m = m8 * 4;
                    r0 = __builtin_amdgcn_fdot2(p0, wr[m + 0], r0, false);
                    r1 = __builtin_amdgcn_fdot2(p1, wr[m + 1], r1, false);
                    r0 = __builtin_amdgcn_fdot2(p2, wr[m + 2], r0, false);
                    r1 = __builtin_amdgcn_fdot2(p3, wr[m + 3], r1, false);
                    u0 = __builtin_amdgcn_fdot2(p0, wu[m + 0], u0, false);
                    u1 = __builtin_amdgcn_fdot2(p1, wu[m + 1], u1, false);
                    u0 = __builtin_amdgcn_fdot2(p2, wu[m + 2], u0, false);
                    u1 = __builtin_amdgcn_fdot2(p3, wu[m + 3], u1, false);
                }
                const float rg = fast_sigmoid(r0 + r1);
                const float ug = fast_sigmoid(u0 + u1);

                s_rh[j] = (_Float16)(rg * h);
                wave_lds_fence();

                float c0 = pc, c1 = 0.f;
                const half8v* rv = (const half8v*)s_rh;
#pragma unroll
                for (int m8 = 0; m8 < 8; ++m8) {
                    const half8v v = rv[m8];
                    const half2v p0 = __builtin_shufflevector(v, v, 0, 1);
                    const half2v p1 = __builtin_shufflevector(v, v, 2, 3);
                    const half2v p2 = __builtin_shufflevector(v, v, 4, 5);
                    const half2v p3 = __builtin_shufflevector(v, v, 6, 7);
                    const int m = m8 * 4;
                    c0 = __builtin_amdgcn_fdot2(p0, wc[m + 0], c0, false);
                    c1 = __builtin_amdgcn_fdot2(p1, wc[m + 1], c1, false);
                    c0 = __builtin_amdgcn_fdot2(p2, wc[m + 2], c0, false);
                    c1 = __builtin_amdgcn_fdot2(p3, wc[m + 3], c1, false);
                }
                const float cg = fast_tanh(c0 + c1);

                const float uh = (1.0f - a) * ug;
                h = uh * h + (1.0f - uh) * cg;
                orow[t * Hn + j] = h;
                wave_lds_fence();  // WAR before next t's s_h/s_rh writes
            }
        }
    }

    // ---- zero tail: out[b, len:T, :] = 0 ----
    float4 z;
    z.x = z.y = z.z = z.w = 0.0f;
    float* tail = orow + len * Hn;
    const int total = (Tn - len) * Hn;
    for (int i = tid * 4; i < total; i += 128 * 4) {
        *(float4*)(tail + i) = z;
    }
}

extern "C" void kernel_launch(void* const* d_in, const int* in_sizes, int n_in,
                              void* d_out, int out_size, void* d_ws, size_t ws_size,
                              hipStream_t stream) {
    const float* x    = (const float*)d_in[0];
    const int*   slen = (const int*)  d_in[1];
    const float* att  = (const float*)d_in[2];
    const float* gk   = (const float*)d_in[3];
    const float* gb   = (const float*)d_in[4];
    const float* ck   = (const float*)d_in[5];
    const float* cb   = (const float*)d_in[6];
    float* out = (float*)d_out;

    const int B = in_sizes[1];  // 2048
    augru_fused<<<B, 128, 0, stream>>>(x, slen, att, gk, gb, ck, cb, out);
}